// Round 7
// baseline (339.678 us; speedup 1.0000x reference)
//
#include <hip/hip_runtime.h>
#include <cstddef>

#define G 64
#define NPG 1024
#define NNODES 65536
#define NEDGE 1048576
#define BCAP 48                // per-node bucket capacity; deg~Poisson(16), P(>=48)~6e-11/node
#define LCAP 32                // LDS-cached col entries per node; P(deg>32)~1e-4/node -> global fallback
#define HSTR 20                // padded LDS row stride for h (floats); 80B rows, 16B aligned
#define ZTR 1028               // transposed z-tile d-row stride (floats); 16B-aligned, bank-staggered
#define ADJ_ELEMS 67108864ull  // 64*1024*1024
#define BM_WORDS 2097152       // 64 graphs * 1024*1024 bits / 32 = 8 MB bitmap

typedef float f32x4 __attribute__((ext_vector_type(4)));
typedef float f32x2 __attribute__((ext_vector_type(2)));
typedef unsigned u32x4 __attribute__((ext_vector_type(4)));

// ---------------- K1: ONE pass over edges: bucket fill + edge bitmap ----------------
// int4-vectorized edge reads: 4 edges per thread, 2x 16B loads.
// (cnt/ebm/acc/done pre-zeroed by a single hipMemsetAsync -- no init kernel.)
__global__ __launch_bounds__(256) void k_build(const int* __restrict__ ei,
                                               int* __restrict__ cnt,
                                               unsigned short* __restrict__ colb,
                                               unsigned* __restrict__ bm) {
  int t = blockIdx.x * 256 + threadIdx.x;          // grid 1024 -> 262144 threads, 4 edges each
  const int4* sp = (const int4*)ei;
  const int4* dp = (const int4*)(ei + NEDGE);
  int4 s4 = sp[t];
  int4 d4 = dp[t];
  int ss[4] = {s4.x, s4.y, s4.z, s4.w};
  int dd[4] = {d4.x, d4.y, d4.z, d4.w};
  #pragma unroll
  for (int q = 0; q < 4; ++q) {
    int src = ss[q], dst = dd[q];
    int p = atomicAdd(&cnt[dst], 1);
    if (p < BCAP) colb[(size_t)dst * BCAP + p] = (unsigned short)(src & (NPG - 1));
    int gg = src >> 10, ls = src & (NPG - 1), ld = dst & (NPG - 1);
    atomicOr(&bm[gg * 32768 + ls * 32 + (ld >> 5)], 1u << (ld & 31));
  }
}

// ---------------- K2: GIN encoder (blocks 0..63) + dense_adj writing (blocks 64+) ----------------
__global__ __launch_bounds__(1024) void k_gin(
    const float* __restrict__ x, const float* __restrict__ eps,
    const int* __restrict__ cnt, const unsigned short* __restrict__ colb,
    const float* __restrict__ W0a, const float* __restrict__ b0a,
    const float* __restrict__ W0b, const float* __restrict__ b0b,
    const float* __restrict__ Wa, const float* __restrict__ ba,
    const float* __restrict__ Wb, const float* __restrict__ bb,
    const float* __restrict__ Wm, const float* __restrict__ bm_,
    const float* __restrict__ Ws, const float* __restrict__ bs,
    const unsigned* __restrict__ ebm,
    float* __restrict__ zbuf, float* __restrict__ acc, float* __restrict__ out) {
  __shared__ float hbuf[NPG * HSTR];            // 80 KB
  __shared__ unsigned short colc[NPG * LCAP];   // 64 KB, TRANSPOSED: colc[k*NPG + node]
  __shared__ float red[16];

  if (blockIdx.x >= G) {
    // write final dense_adj from bitmap (overlaps with GIN work)
    f32x4* dz = (f32x4*)(out + 2 + ADJ_ELEMS);
    size_t i = (size_t)(blockIdx.x - G) * 1024 + threadIdx.x;
    size_t stride = (size_t)(gridDim.x - G) * 1024;
    for (; i < ADJ_ELEMS / 4; i += stride) {
      unsigned w = ebm[i >> 3];
      int sh = ((int)i & 7) << 2;
      f32x4 v;
      v.x = ((w >> (sh + 0)) & 1) ? 1.f : 0.f;
      v.y = ((w >> (sh + 1)) & 1) ? 1.f : 0.f;
      v.z = ((w >> (sh + 2)) & 1) ? 1.f : 0.f;
      v.w = ((w >> (sh + 3)) & 1) ? 1.f : 0.f;
      __builtin_nontemporal_store(v, &dz[i]);
    }
    return;
  }

  const int g = blockIdx.x;
  const int tid = threadIdx.x;
  const int dv0 = cnt[g * NPG + tid];
  const int dv = (dv0 < BCAP) ? dv0 : BCAP;     // never triggers for this input
  const int dvl = (dv < LCAP) ? dv : LCAP;      // LDS-cached portion
  const unsigned short* cl = colb + (size_t)(g * NPG + tid) * BCAP;  // global fallback (k>=LCAP)

  // cache own node's first 32 col entries into transposed LDS (own column -> no barrier needed)
  {
    const uint4* rowp = (const uint4*)(colb + (size_t)(g * NPG + tid) * BCAP);  // 96B rows, 16B aligned
    #pragma unroll
    for (int q = 0; q < 4; ++q) {
      uint4 w4 = rowp[q];
      unsigned ws0 = w4.x, ws1 = w4.y, ws2 = w4.z, ws3 = w4.w;
      colc[(q * 8 + 0) * NPG + tid] = (unsigned short)(ws0 & 0xffff);
      colc[(q * 8 + 1) * NPG + tid] = (unsigned short)(ws0 >> 16);
      colc[(q * 8 + 2) * NPG + tid] = (unsigned short)(ws1 & 0xffff);
      colc[(q * 8 + 3) * NPG + tid] = (unsigned short)(ws1 >> 16);
      colc[(q * 8 + 4) * NPG + tid] = (unsigned short)(ws2 & 0xffff);
      colc[(q * 8 + 5) * NPG + tid] = (unsigned short)(ws2 >> 16);
      colc[(q * 8 + 6) * NPG + tid] = (unsigned short)(ws3 & 0xffff);
      colc[(q * 8 + 7) * NPG + tid] = (unsigned short)(ws3 >> 16);
    }
  }

  // load x -> hbuf (h0 = x)
  {
    const float4* xg = (const float4*)(x + (size_t)g * (NPG * 16));
    for (int idx = tid; idx < NPG * 4; idx += 1024) {
      float4 v = xg[idx];
      *(float4*)(hbuf + (idx >> 2) * HSTR + (idx & 3) * 4) = v;
    }
  }
  __syncthreads();

  for (int l = 0; l < 10; ++l) {
    const float* Aw = (l == 0) ? W0a : Wa + (l - 1) * 256;
    const float* Ab = (l == 0) ? b0a : ba + (l - 1) * 16;
    const float* Bw = (l == 0) ? W0b : Wb + (l - 1) * 256;
    const float* Bb = (l == 0) ? b0b : bb + (l - 1) * 16;

    // gather: agg = h[dst] + sum_{src in N(dst)} h[src], in registers
    float4 a0 = *(const float4*)(hbuf + tid * HSTR + 0);
    float4 a1 = *(const float4*)(hbuf + tid * HSTR + 4);
    float4 a2 = *(const float4*)(hbuf + tid * HSTR + 8);
    float4 a3 = *(const float4*)(hbuf + tid * HSTR + 12);
    for (int k = 0; k < dvl; ++k) {
      int ls = colc[k * NPG + tid];              // conflict-free LDS read (lanes consecutive)
      const float* hp = hbuf + ls * HSTR;
      float4 v0 = *(const float4*)(hp + 0);
      float4 v1 = *(const float4*)(hp + 4);
      float4 v2 = *(const float4*)(hp + 8);
      float4 v3 = *(const float4*)(hp + 12);
      a0.x += v0.x; a0.y += v0.y; a0.z += v0.z; a0.w += v0.w;
      a1.x += v1.x; a1.y += v1.y; a1.z += v1.z; a1.w += v1.w;
      a2.x += v2.x; a2.y += v2.y; a2.z += v2.z; a2.w += v2.w;
      a3.x += v3.x; a3.y += v3.y; a3.z += v3.z; a3.w += v3.w;
    }
    for (int k = LCAP; k < dv; ++k) {            // rare overflow (P ~ 1e-4/node)
      int ls = cl[k];
      const float* hp = hbuf + ls * HSTR;
      float4 v0 = *(const float4*)(hp + 0);
      float4 v1 = *(const float4*)(hp + 4);
      float4 v2 = *(const float4*)(hp + 8);
      float4 v3 = *(const float4*)(hp + 12);
      a0.x += v0.x; a0.y += v0.y; a0.z += v0.z; a0.w += v0.w;
      a1.x += v1.x; a1.y += v1.y; a1.z += v1.z; a1.w += v1.w;
      a2.x += v2.x; a2.y += v2.y; a2.z += v2.z; a2.w += v2.w;
      a3.x += v3.x; a3.y += v3.y; a3.z += v3.z; a3.w += v3.w;
    }
    float aa[16] = {a0.x, a0.y, a0.z, a0.w, a1.x, a1.y, a1.z, a1.w,
                    a2.x, a2.y, a2.z, a2.w, a3.x, a3.y, a3.z, a3.w};

    // MLP with scalar-loaded (SGPR) weights
    float u[16], v[16];
    #pragma unroll
    for (int j = 0; j < 16; ++j) u[j] = Ab[j];
    #pragma unroll
    for (int i = 0; i < 16; ++i) {
      float ai = aa[i];
      #pragma unroll
      for (int j = 0; j < 16; ++j) u[j] += ai * Aw[i * 16 + j];
    }
    #pragma unroll
    for (int j = 0; j < 16; ++j) u[j] = fmaxf(u[j], 0.f);
    #pragma unroll
    for (int j = 0; j < 16; ++j) v[j] = Bb[j];
    #pragma unroll
    for (int i = 0; i < 16; ++i) {
      float ui = u[i];
      #pragma unroll
      for (int j = 0; j < 16; ++j) v[j] += ui * Bw[i * 16 + j];
    }
    const bool rl = (l != 9);   // relu after every conv except the last
    __syncthreads();            // all gathers of old h done before overwrite
    #pragma unroll
    for (int j4 = 0; j4 < 4; ++j4) {
      float4 w;
      w.x = rl ? fmaxf(v[j4 * 4 + 0], 0.f) : v[j4 * 4 + 0];
      w.y = rl ? fmaxf(v[j4 * 4 + 1], 0.f) : v[j4 * 4 + 1];
      w.z = rl ? fmaxf(v[j4 * 4 + 2], 0.f) : v[j4 * 4 + 2];
      w.w = rl ? fmaxf(v[j4 * 4 + 3], 0.f) : v[j4 * 4 + 3];
      *(float4*)(hbuf + tid * HSTR + j4 * 4) = w;
    }
    __syncthreads();
  }

  // ---- heads: mu, std=softplus, z = mu + std*eps, KL (weights via SGPR loads) ----
  float hv[16];
  #pragma unroll
  for (int i = 0; i < 16; ++i) hv[i] = hbuf[tid * HSTR + i];  // own row, just wrote it

  float mu[8], st[8];
  #pragma unroll
  for (int m = 0; m < 8; ++m) { mu[m] = bm_[m]; st[m] = bs[m]; }
  #pragma unroll
  for (int i = 0; i < 16; ++i) {
    float hi = hv[i];
    #pragma unroll
    for (int m = 0; m < 8; ++m) { mu[m] += hi * Wm[i * 8 + m]; st[m] += hi * Ws[i * 8 + m]; }
  }
  #pragma unroll
  for (int m = 0; m < 8; ++m) {
    float s = st[m];
    st[m] = fmaxf(s, 0.f) + log1pf(__expf(-fabsf(s)));  // stable softplus, keeps tail
  }
  int gid = g * NPG + tid;
  float4 e0 = *(const float4*)(eps + (size_t)gid * 8);
  float4 e1 = *(const float4*)(eps + (size_t)gid * 8 + 4);
  float ev[8] = {e0.x, e0.y, e0.z, e0.w, e1.x, e1.y, e1.z, e1.w};
  float zv[8];
  float klp = 0.f;
  #pragma unroll
  for (int m = 0; m < 8; ++m) {
    zv[m] = mu[m] + st[m] * ev[m];
    klp += -__logf(st[m]) + 0.5f * (st[m] * st[m] + mu[m] * mu[m]) - 0.5f;
  }
  *(float4*)(zbuf + (size_t)gid * 8) = make_float4(zv[0], zv[1], zv[2], zv[3]);
  *(float4*)(zbuf + (size_t)gid * 8 + 4) = make_float4(zv[4], zv[5], zv[6], zv[7]);

  for (int o = 32; o > 0; o >>= 1) klp += __shfl_down(klp, o, 64);
  if ((tid & 63) == 0) red[tid >> 6] = klp;
  __syncthreads();
  if (tid == 0) {
    float s = 0.f;
    for (int i = 0; i < 16; ++i) s += red[i];
    atomicAdd(&acc[1], s);
  }
}

// per-element BCE term with torch's -100 clamp semantics; returns p, accumulates selected term
__device__ __forceinline__ float elem_p(float sv, int bit, float& accl) {
  float t = __expf(-sv);
  float p = __builtin_amdgcn_rcpf(1.f + t);
  float lp, lm;
  if (t > 3.0e38f)             { lp = -100.f; lm = 0.f; }     // p==0
  else if (t < 5.9604645e-08f) { lp = 0.f;    lm = -100.f; }  // p==1 (t < 2^-24)
  else { float q = __logf(1.f + t); lp = -q; lm = -sv - q; }
  accl += bit ? lp : lm;
  return p;
}

// ---------------- K3: adj_pred + full nll via bitmap + fence-free fused finalize ----------------
// jp outer, 4x4 register outer-tile inner; zr loaded once per jp (32 ds_read_b128/thread).
// Finalize: per-block returning atomicAdd(acc) -> wave-local vmcnt(0) drain -> done++.
// NO __threadfence anywhere (R2 lesson: per-block device fences = buffer_wbl2 storm).
// Atomics serialize at the device coherence point, so done==N-1 implies all acc adds landed;
// the last block re-reads acc with atomic RMWs (+0.0f) and writes the two scalars.
__global__ __launch_bounds__(256) void k_adj(const float* __restrict__ zbuf,
                                             const unsigned* __restrict__ ebm,
                                             float* __restrict__ out,
                                             float* __restrict__ acc,
                                             int* __restrict__ done) {
  __shared__ float zt[8 * ZTR];   // 32.9 KB
  __shared__ float red[4];
  const int tid = threadIdx.x;
  const int g = blockIdx.x >> 6;
  const int i0 = (blockIdx.x & 63) << 4;

  // fill transposed tile: zt[d][j] = z[j][d]
  {
    const float4* zg = (const float4*)(zbuf + (size_t)g * (NPG * 8));
    #pragma unroll
    for (int it = 0; it < 8; ++it) {
      int idx = tid + it * 256;            // 0..2047 float4s
      float4 v = zg[idx];
      int j = idx >> 1, db = (idx & 1) << 2;
      zt[(db + 0) * ZTR + j] = v.x;
      zt[(db + 1) * ZTR + j] = v.y;
      zt[(db + 2) * ZTR + j] = v.z;
      zt[(db + 3) * ZTR + j] = v.w;
    }
  }
  __syncthreads();

  const int w = tid >> 6;    // wave 0..3 owns rows ib..ib+3
  const int l = tid & 63;
  const int ib = i0 + (w << 2);
  float accl = 0.f;

  // preload the wave's 4 zi rows into registers (broadcast LDS reads)
  float zi[4][8];
  #pragma unroll
  for (int r = 0; r < 4; ++r)
    #pragma unroll
    for (int d = 0; d < 8; ++d) zi[r][d] = zt[d * ZTR + ib + r];

  const unsigned* bmr = ebm + g * 32768 + ib * 32;       // 4 rows of bits, +32 words each
  float* obase = out + 2 + (size_t)g * (NPG * NPG) + (size_t)ib * NPG;

  #pragma unroll
  for (int jp = 0; jp < 4; ++jp) {
    const int j0 = (l << 2) + (jp << 8);
    float4 zr[8];
    #pragma unroll
    for (int d = 0; d < 8; ++d) zr[d] = *(const float4*)(zt + d * ZTR + j0);
    #pragma unroll
    for (int r = 0; r < 4; ++r) {
      float s0 = 0.f, s1 = 0.f, s2 = 0.f, s3 = 0.f;
      #pragma unroll
      for (int d = 0; d < 8; ++d) {
        float zd = zi[r][d];
        s0 += zd * zr[d].x; s1 += zd * zr[d].y; s2 += zd * zr[d].z; s3 += zd * zr[d].w;
      }
      unsigned bits = (bmr[r * 32 + (j0 >> 5)] >> (j0 & 31)) & 15u;
      float p0 = elem_p(s0, bits & 1, accl);
      float p1 = elem_p(s1, (bits >> 1) & 1, accl);
      float p2 = elem_p(s2, (bits >> 2) & 1, accl);
      float p3 = elem_p(s3, (bits >> 3) & 1, accl);
      f32x2 v0 = {p0, p1}, v1 = {p2, p3};
      f32x2* dp = (f32x2*)(obase + (size_t)r * NPG + j0);   // 8B aligned
      __builtin_nontemporal_store(v0, &dp[0]);
      __builtin_nontemporal_store(v1, &dp[1]);
    }
  }

  for (int o = 32; o > 0; o >>= 1) accl += __shfl_down(accl, o, 64);
  if (l == 0) red[w] = accl;
  __syncthreads();
  if (tid == 0) {
    float mine = red[0] + red[1] + red[2] + red[3];
    (void)__hip_atomic_fetch_add(&acc[0], mine, __ATOMIC_RELAXED, __HIP_MEMORY_SCOPE_AGENT);
    asm volatile("s_waitcnt vmcnt(0)" ::: "memory");   // acc add performed at coherence point
    int d = __hip_atomic_fetch_add(done, 1, __ATOMIC_RELAXED, __HIP_MEMORY_SCOPE_AGENT);
    if (d == (int)gridDim.x - 1) {                     // last block: all acc adds are visible
      float nll = __hip_atomic_fetch_add(&acc[0], 0.0f, __ATOMIC_RELAXED, __HIP_MEMORY_SCOPE_AGENT);
      float kl  = __hip_atomic_fetch_add(&acc[1], 0.0f, __ATOMIC_RELAXED, __HIP_MEMORY_SCOPE_AGENT);
      out[0] = -nll;
      out[1] = kl;
    }
  }
}

extern "C" void kernel_launch(void* const* d_in, const int* in_sizes, int n_in,
                              void* d_out, int out_size, void* d_ws, size_t ws_size,
                              hipStream_t stream) {
  const float* x   = (const float*)d_in[0];
  const float* eps = (const float*)d_in[1];
  const int*   ei  = (const int*)d_in[2];
  // d_in[3] = num_graphs (64, hardcoded)
  const float* W0a = (const float*)d_in[4];
  const float* b0a = (const float*)d_in[5];
  const float* W0b = (const float*)d_in[6];
  const float* b0b = (const float*)d_in[7];
  const float* Wa  = (const float*)d_in[8];
  const float* ba  = (const float*)d_in[9];
  const float* Wb  = (const float*)d_in[10];
  const float* bb  = (const float*)d_in[11];
  const float* Wm  = (const float*)d_in[12];
  const float* bm  = (const float*)d_in[13];
  const float* Ws  = (const float*)d_in[14];
  const float* bs  = (const float*)d_in[15];
  float* out = (float*)d_out;

  // ws layout: zeroed span FIRST (cnt | ebm | acc+done), then colb | zbuf.
  // 262144 + 8388608 + 16 = 8650768 bytes, 16B-aligned throughout.
  unsigned char* base  = (unsigned char*)d_ws;
  int* cnt             = (int*)base;                                // 256 KB
  unsigned* ebm        = (unsigned*)(base + 262144);                // 8 MB
  float* acc           = (float*)(base + 262144 + 8388608);         // acc[0]=nll, acc[1]=kl
  int* done            = (int*)(acc + 2);                           // done counter
  unsigned short* colb = (unsigned short*)(base + 8650768);         // 6 MB (96B rows, 16B-aligned)
  float* zbuf          = (float*)(base + 8650768 + 6291456);        // 2 MB

  hipMemsetAsync(base, 0, 8650768, stream);   // cnt + ebm + acc + done in one driver fill
  k_build<<<1024, 256, 0, stream>>>(ei, cnt, colb, ebm);
  k_gin<<<256, 1024, 0, stream>>>(x, eps, cnt, colb,
                                  W0a, b0a, W0b, b0b, Wa, ba, Wb, bb,
                                  Wm, bm, Ws, bs, ebm, zbuf, acc, out);
  k_adj<<<4096, 256, 0, stream>>>(zbuf, ebm, out, acc, done);
}

// Round 8
// 324.292 us; speedup vs baseline: 1.0474x; 1.0474x over previous
//
#include <hip/hip_runtime.h>
#include <cstddef>

#define G 64
#define NPG 1024
#define NNODES 65536
#define NEDGE 1048576
#define BCAP 48                // per-node bucket capacity; deg~Poisson(16), P(>=48)~6e-11/node
#define LCAP 32                // LDS-cached col entries per node; P(deg>32)~1e-4/node -> global fallback
#define HSTR 20                // padded LDS row stride for h (floats); 80B rows, 16B aligned
#define ZTR 1028               // transposed z-tile d-row stride (floats); 16B-aligned, bank-staggered
#define ADJ_ELEMS 67108864ull  // 64*1024*1024
#define BM_WORDS 2097152       // 64 graphs * 1024*1024 bits / 32 = 8 MB bitmap

typedef float f32x4 __attribute__((ext_vector_type(4)));
typedef float f32x2 __attribute__((ext_vector_type(2)));
typedef unsigned u32x4 __attribute__((ext_vector_type(4)));

// ---------------- K1: zero bucket counts + accumulators + edge bitmap ----------------
__global__ __launch_bounds__(1024) void k_init(int* __restrict__ cnt, float* __restrict__ acc,
                                               unsigned* __restrict__ bm) {
  int i = blockIdx.x * 1024 + threadIdx.x;
  cnt[i] = 0;
  if (i < 2) acc[i] = 0.0f;
  u32x4 z = {0u, 0u, 0u, 0u};
  u32x4* b4 = (u32x4*)bm;
  for (int k = i; k < BM_WORDS / 4; k += 65536) b4[k] = z;   // 8 iters, 8 MB
}

// ---------------- K2: ONE pass over edges: bucket fill + edge bitmap ----------------
// int4-vectorized edge reads: 4 edges per thread, 2x 16B loads.
__global__ __launch_bounds__(256) void k_build(const int* __restrict__ ei,
                                               int* __restrict__ cnt,
                                               unsigned short* __restrict__ colb,
                                               unsigned* __restrict__ bm) {
  int t = blockIdx.x * 256 + threadIdx.x;          // grid 1024 -> 262144 threads, 4 edges each
  const int4* sp = (const int4*)ei;
  const int4* dp = (const int4*)(ei + NEDGE);
  int4 s4 = sp[t];
  int4 d4 = dp[t];
  int ss[4] = {s4.x, s4.y, s4.z, s4.w};
  int dd[4] = {d4.x, d4.y, d4.z, d4.w};
  #pragma unroll
  for (int q = 0; q < 4; ++q) {
    int src = ss[q], dst = dd[q];
    int p = atomicAdd(&cnt[dst], 1);
    if (p < BCAP) colb[(size_t)dst * BCAP + p] = (unsigned short)(src & (NPG - 1));
    int gg = src >> 10, ls = src & (NPG - 1), ld = dst & (NPG - 1);
    atomicOr(&bm[gg * 32768 + ls * 32 + (ld >> 5)], 1u << (ld & 31));
  }
}

// ---------------- K3: GIN encoder (blocks 0..63) + dense_adj writing (blocks 64+) ----------------
__global__ __launch_bounds__(1024) void k_gin(
    const float* __restrict__ x, const float* __restrict__ eps,
    const int* __restrict__ cnt, const unsigned short* __restrict__ colb,
    const float* __restrict__ W0a, const float* __restrict__ b0a,
    const float* __restrict__ W0b, const float* __restrict__ b0b,
    const float* __restrict__ Wa, const float* __restrict__ ba,
    const float* __restrict__ Wb, const float* __restrict__ bb,
    const float* __restrict__ Wm, const float* __restrict__ bm_,
    const float* __restrict__ Ws, const float* __restrict__ bs,
    const unsigned* __restrict__ ebm,
    float* __restrict__ zbuf, float* __restrict__ acc, float* __restrict__ out) {
  __shared__ float hbuf[NPG * HSTR];            // 80 KB
  __shared__ unsigned short colc[NPG * LCAP];   // 64 KB, TRANSPOSED: colc[k*NPG + node]
  __shared__ float red[16];

  if (blockIdx.x >= G) {
    // write final dense_adj from bitmap (overlaps with GIN work)
    f32x4* dz = (f32x4*)(out + 2 + ADJ_ELEMS);
    size_t i = (size_t)(blockIdx.x - G) * 1024 + threadIdx.x;
    size_t stride = (size_t)(gridDim.x - G) * 1024;
    for (; i < ADJ_ELEMS / 4; i += stride) {
      unsigned w = ebm[i >> 3];
      int sh = ((int)i & 7) << 2;
      f32x4 v;
      v.x = ((w >> (sh + 0)) & 1) ? 1.f : 0.f;
      v.y = ((w >> (sh + 1)) & 1) ? 1.f : 0.f;
      v.z = ((w >> (sh + 2)) & 1) ? 1.f : 0.f;
      v.w = ((w >> (sh + 3)) & 1) ? 1.f : 0.f;
      __builtin_nontemporal_store(v, &dz[i]);
    }
    return;
  }

  const int g = blockIdx.x;
  const int tid = threadIdx.x;
  const int dv0 = cnt[g * NPG + tid];
  const int dv = (dv0 < BCAP) ? dv0 : BCAP;     // never triggers for this input
  const int dvl = (dv < LCAP) ? dv : LCAP;      // LDS-cached portion
  const unsigned short* cl = colb + (size_t)(g * NPG + tid) * BCAP;  // global fallback (k>=LCAP)

  // cache own node's first 32 col entries into transposed LDS (own column -> no barrier needed)
  {
    const uint4* rowp = (const uint4*)(colb + (size_t)(g * NPG + tid) * BCAP);  // 96B rows, 16B aligned
    #pragma unroll
    for (int q = 0; q < 4; ++q) {
      uint4 w4 = rowp[q];
      unsigned ws0 = w4.x, ws1 = w4.y, ws2 = w4.z, ws3 = w4.w;
      colc[(q * 8 + 0) * NPG + tid] = (unsigned short)(ws0 & 0xffff);
      colc[(q * 8 + 1) * NPG + tid] = (unsigned short)(ws0 >> 16);
      colc[(q * 8 + 2) * NPG + tid] = (unsigned short)(ws1 & 0xffff);
      colc[(q * 8 + 3) * NPG + tid] = (unsigned short)(ws1 >> 16);
      colc[(q * 8 + 4) * NPG + tid] = (unsigned short)(ws2 & 0xffff);
      colc[(q * 8 + 5) * NPG + tid] = (unsigned short)(ws2 >> 16);
      colc[(q * 8 + 6) * NPG + tid] = (unsigned short)(ws3 & 0xffff);
      colc[(q * 8 + 7) * NPG + tid] = (unsigned short)(ws3 >> 16);
    }
  }

  // load x -> hbuf (h0 = x)
  {
    const float4* xg = (const float4*)(x + (size_t)g * (NPG * 16));
    for (int idx = tid; idx < NPG * 4; idx += 1024) {
      float4 v = xg[idx];
      *(float4*)(hbuf + (idx >> 2) * HSTR + (idx & 3) * 4) = v;
    }
  }
  __syncthreads();

  for (int l = 0; l < 10; ++l) {
    const float* Aw = (l == 0) ? W0a : Wa + (l - 1) * 256;
    const float* Ab = (l == 0) ? b0a : ba + (l - 1) * 16;
    const float* Bw = (l == 0) ? W0b : Wb + (l - 1) * 256;
    const float* Bb = (l == 0) ? b0b : bb + (l - 1) * 16;

    // gather: agg = h[dst] + sum_{src in N(dst)} h[src], in registers.
    // Unrolled by 2 with both indices prefetched: deeper LDS pipeline, identical add order.
    float4 a0 = *(const float4*)(hbuf + tid * HSTR + 0);
    float4 a1 = *(const float4*)(hbuf + tid * HSTR + 4);
    float4 a2 = *(const float4*)(hbuf + tid * HSTR + 8);
    float4 a3 = *(const float4*)(hbuf + tid * HSTR + 12);
    int k = 0;
    for (; k + 1 < dvl; k += 2) {
      int ls0 = colc[k * NPG + tid];             // conflict-free LDS reads (lanes consecutive)
      int ls1 = colc[(k + 1) * NPG + tid];
      const float* hp0 = hbuf + ls0 * HSTR;
      const float* hp1 = hbuf + ls1 * HSTR;
      float4 v00 = *(const float4*)(hp0 + 0);
      float4 v01 = *(const float4*)(hp0 + 4);
      float4 v02 = *(const float4*)(hp0 + 8);
      float4 v03 = *(const float4*)(hp0 + 12);
      float4 v10 = *(const float4*)(hp1 + 0);
      float4 v11 = *(const float4*)(hp1 + 4);
      float4 v12 = *(const float4*)(hp1 + 8);
      float4 v13 = *(const float4*)(hp1 + 12);
      a0.x += v00.x; a0.y += v00.y; a0.z += v00.z; a0.w += v00.w;
      a1.x += v01.x; a1.y += v01.y; a1.z += v01.z; a1.w += v01.w;
      a2.x += v02.x; a2.y += v02.y; a2.z += v02.z; a2.w += v02.w;
      a3.x += v03.x; a3.y += v03.y; a3.z += v03.z; a3.w += v03.w;
      a0.x += v10.x; a0.y += v10.y; a0.z += v10.z; a0.w += v10.w;
      a1.x += v11.x; a1.y += v11.y; a1.z += v11.z; a1.w += v11.w;
      a2.x += v12.x; a2.y += v12.y; a2.z += v12.z; a2.w += v12.w;
      a3.x += v13.x; a3.y += v13.y; a3.z += v13.z; a3.w += v13.w;
    }
    if (k < dvl) {                               // odd tail
      int ls = colc[k * NPG + tid];
      const float* hp = hbuf + ls * HSTR;
      float4 v0 = *(const float4*)(hp + 0);
      float4 v1 = *(const float4*)(hp + 4);
      float4 v2 = *(const float4*)(hp + 8);
      float4 v3 = *(const float4*)(hp + 12);
      a0.x += v0.x; a0.y += v0.y; a0.z += v0.z; a0.w += v0.w;
      a1.x += v1.x; a1.y += v1.y; a1.z += v1.z; a1.w += v1.w;
      a2.x += v2.x; a2.y += v2.y; a2.z += v2.z; a2.w += v2.w;
      a3.x += v3.x; a3.y += v3.y; a3.z += v3.z; a3.w += v3.w;
    }
    for (int kk = LCAP; kk < dv; ++kk) {         // rare overflow (P ~ 1e-4/node)
      int ls = cl[kk];
      const float* hp = hbuf + ls * HSTR;
      float4 v0 = *(const float4*)(hp + 0);
      float4 v1 = *(const float4*)(hp + 4);
      float4 v2 = *(const float4*)(hp + 8);
      float4 v3 = *(const float4*)(hp + 12);
      a0.x += v0.x; a0.y += v0.y; a0.z += v0.z; a0.w += v0.w;
      a1.x += v1.x; a1.y += v1.y; a1.z += v1.z; a1.w += v1.w;
      a2.x += v2.x; a2.y += v2.y; a2.z += v2.z; a2.w += v2.w;
      a3.x += v3.x; a3.y += v3.y; a3.z += v3.z; a3.w += v3.w;
    }
    float aa[16] = {a0.x, a0.y, a0.z, a0.w, a1.x, a1.y, a1.z, a1.w,
                    a2.x, a2.y, a2.z, a2.w, a3.x, a3.y, a3.z, a3.w};

    // MLP with scalar-loaded (SGPR) weights
    float u[16], v[16];
    #pragma unroll
    for (int j = 0; j < 16; ++j) u[j] = Ab[j];
    #pragma unroll
    for (int i = 0; i < 16; ++i) {
      float ai = aa[i];
      #pragma unroll
      for (int j = 0; j < 16; ++j) u[j] += ai * Aw[i * 16 + j];
    }
    #pragma unroll
    for (int j = 0; j < 16; ++j) u[j] = fmaxf(u[j], 0.f);
    #pragma unroll
    for (int j = 0; j < 16; ++j) v[j] = Bb[j];
    #pragma unroll
    for (int i = 0; i < 16; ++i) {
      float ui = u[i];
      #pragma unroll
      for (int j = 0; j < 16; ++j) v[j] += ui * Bw[i * 16 + j];
    }
    const bool rl = (l != 9);   // relu after every conv except the last
    __syncthreads();            // all gathers of old h done before overwrite
    #pragma unroll
    for (int j4 = 0; j4 < 4; ++j4) {
      float4 w;
      w.x = rl ? fmaxf(v[j4 * 4 + 0], 0.f) : v[j4 * 4 + 0];
      w.y = rl ? fmaxf(v[j4 * 4 + 1], 0.f) : v[j4 * 4 + 1];
      w.z = rl ? fmaxf(v[j4 * 4 + 2], 0.f) : v[j4 * 4 + 2];
      w.w = rl ? fmaxf(v[j4 * 4 + 3], 0.f) : v[j4 * 4 + 3];
      *(float4*)(hbuf + tid * HSTR + j4 * 4) = w;
    }
    __syncthreads();
  }

  // ---- heads: mu, std=softplus, z = mu + std*eps, KL (weights via SGPR loads) ----
  float hv[16];
  #pragma unroll
  for (int i = 0; i < 16; ++i) hv[i] = hbuf[tid * HSTR + i];  // own row, just wrote it

  float mu[8], st[8];
  #pragma unroll
  for (int m = 0; m < 8; ++m) { mu[m] = bm_[m]; st[m] = bs[m]; }
  #pragma unroll
  for (int i = 0; i < 16; ++i) {
    float hi = hv[i];
    #pragma unroll
    for (int m = 0; m < 8; ++m) { mu[m] += hi * Wm[i * 8 + m]; st[m] += hi * Ws[i * 8 + m]; }
  }
  #pragma unroll
  for (int m = 0; m < 8; ++m) {
    float s = st[m];
    st[m] = fmaxf(s, 0.f) + log1pf(__expf(-fabsf(s)));  // stable softplus, keeps tail
  }
  int gid = g * NPG + tid;
  float4 e0 = *(const float4*)(eps + (size_t)gid * 8);
  float4 e1 = *(const float4*)(eps + (size_t)gid * 8 + 4);
  float ev[8] = {e0.x, e0.y, e0.z, e0.w, e1.x, e1.y, e1.z, e1.w};
  float zv[8];
  float klp = 0.f;
  #pragma unroll
  for (int m = 0; m < 8; ++m) {
    zv[m] = mu[m] + st[m] * ev[m];
    klp += -__logf(st[m]) + 0.5f * (st[m] * st[m] + mu[m] * mu[m]) - 0.5f;
  }
  *(float4*)(zbuf + (size_t)gid * 8) = make_float4(zv[0], zv[1], zv[2], zv[3]);
  *(float4*)(zbuf + (size_t)gid * 8 + 4) = make_float4(zv[4], zv[5], zv[6], zv[7]);

  for (int o = 32; o > 0; o >>= 1) klp += __shfl_down(klp, o, 64);
  if ((tid & 63) == 0) red[tid >> 6] = klp;
  __syncthreads();
  if (tid == 0) {
    float s = 0.f;
    for (int i = 0; i < 16; ++i) s += red[i];
    atomicAdd(&acc[1], s);
  }
}

// per-element BCE term with torch's -100 clamp semantics; returns p, accumulates selected term
__device__ __forceinline__ float elem_p(float sv, int bit, float& accl) {
  float t = __expf(-sv);
  float p = __builtin_amdgcn_rcpf(1.f + t);
  float lp, lm;
  if (t > 3.0e38f)             { lp = -100.f; lm = 0.f; }     // p==0
  else if (t < 5.9604645e-08f) { lp = 0.f;    lm = -100.f; }  // p==1 (t < 2^-24)
  else { float q = __logf(1.f + t); lp = -q; lm = -sv - q; }
  accl += bit ? lp : lm;
  return p;
}

// ---------------- K4: adj_pred + full nll via bitmap ----------------
// jp outer, 4x4 register outer-tile inner; zr loaded once per jp (32 ds_read_b128/thread).
// Stores: float2 NT pairs, wave-contiguous 512B -> full 128B lines.
__global__ __launch_bounds__(256) void k_adj(const float* __restrict__ zbuf,
                                             const unsigned* __restrict__ ebm,
                                             float* __restrict__ out,
                                             float* __restrict__ acc) {
  __shared__ float zt[8 * ZTR];   // 32.9 KB
  __shared__ float red[4];
  const int tid = threadIdx.x;
  const int g = blockIdx.x >> 6;
  const int i0 = (blockIdx.x & 63) << 4;

  // fill transposed tile: zt[d][j] = z[j][d]
  {
    const float4* zg = (const float4*)(zbuf + (size_t)g * (NPG * 8));
    #pragma unroll
    for (int it = 0; it < 8; ++it) {
      int idx = tid + it * 256;            // 0..2047 float4s
      float4 v = zg[idx];
      int j = idx >> 1, db = (idx & 1) << 2;
      zt[(db + 0) * ZTR + j] = v.x;
      zt[(db + 1) * ZTR + j] = v.y;
      zt[(db + 2) * ZTR + j] = v.z;
      zt[(db + 3) * ZTR + j] = v.w;
    }
  }
  __syncthreads();

  const int w = tid >> 6;    // wave 0..3 owns rows ib..ib+3
  const int l = tid & 63;
  const int ib = i0 + (w << 2);
  float accl = 0.f;

  // preload the wave's 4 zi rows into registers (broadcast LDS reads)
  float zi[4][8];
  #pragma unroll
  for (int r = 0; r < 4; ++r)
    #pragma unroll
    for (int d = 0; d < 8; ++d) zi[r][d] = zt[d * ZTR + ib + r];

  const unsigned* bmr = ebm + g * 32768 + ib * 32;       // 4 rows of bits, +32 words each
  float* obase = out + 2 + (size_t)g * (NPG * NPG) + (size_t)ib * NPG;

  #pragma unroll
  for (int jp = 0; jp < 4; ++jp) {
    const int j0 = (l << 2) + (jp << 8);
    float4 zr[8];
    #pragma unroll
    for (int d = 0; d < 8; ++d) zr[d] = *(const float4*)(zt + d * ZTR + j0);
    #pragma unroll
    for (int r = 0; r < 4; ++r) {
      float s0 = 0.f, s1 = 0.f, s2 = 0.f, s3 = 0.f;
      #pragma unroll
      for (int d = 0; d < 8; ++d) {
        float zd = zi[r][d];
        s0 += zd * zr[d].x; s1 += zd * zr[d].y; s2 += zd * zr[d].z; s3 += zd * zr[d].w;
      }
      unsigned bits = (bmr[r * 32 + (j0 >> 5)] >> (j0 & 31)) & 15u;
      float p0 = elem_p(s0, bits & 1, accl);
      float p1 = elem_p(s1, (bits >> 1) & 1, accl);
      float p2 = elem_p(s2, (bits >> 2) & 1, accl);
      float p3 = elem_p(s3, (bits >> 3) & 1, accl);
      f32x2 v0 = {p0, p1}, v1 = {p2, p3};
      f32x2* dp = (f32x2*)(obase + (size_t)r * NPG + j0);   // 8B aligned
      __builtin_nontemporal_store(v0, &dp[0]);
      __builtin_nontemporal_store(v1, &dp[1]);
    }
  }

  for (int o = 32; o > 0; o >>= 1) accl += __shfl_down(accl, o, 64);
  if (l == 0) red[w] = accl;
  __syncthreads();
  if (tid == 0) atomicAdd(&acc[0], red[0] + red[1] + red[2] + red[3]);
}

// ---------------- K5: finalize scalars (separate tiny launch; NO device fences) ----------------
__global__ void k_fin(const float* __restrict__ acc, float* __restrict__ out) {
  if (threadIdx.x == 0 && blockIdx.x == 0) {
    out[0] = -acc[0];   // nll
    out[1] = acc[1];    // kl
  }
}

extern "C" void kernel_launch(void* const* d_in, const int* in_sizes, int n_in,
                              void* d_out, int out_size, void* d_ws, size_t ws_size,
                              hipStream_t stream) {
  const float* x   = (const float*)d_in[0];
  const float* eps = (const float*)d_in[1];
  const int*   ei  = (const int*)d_in[2];
  // d_in[3] = num_graphs (64, hardcoded)
  const float* W0a = (const float*)d_in[4];
  const float* b0a = (const float*)d_in[5];
  const float* W0b = (const float*)d_in[6];
  const float* b0b = (const float*)d_in[7];
  const float* Wa  = (const float*)d_in[8];
  const float* ba  = (const float*)d_in[9];
  const float* Wb  = (const float*)d_in[10];
  const float* bb  = (const float*)d_in[11];
  const float* Wm  = (const float*)d_in[12];
  const float* bm  = (const float*)d_in[13];
  const float* Ws  = (const float*)d_in[14];
  const float* bs  = (const float*)d_in[15];
  float* out = (float*)d_out;

  // ws layout (16B-aligned segments)
  int* cnt             = (int*)d_ws;                         // 65536 ints, 256 KB
  unsigned short* colb = (unsigned short*)(cnt + NNODES);    // 65536*48 u16 = 6 MB (rows 96B, 16B-aligned)
  float* zbuf          = (float*)(colb + (size_t)NNODES * BCAP);  // 65536*8 f32 = 2 MB
  unsigned* ebm        = (unsigned*)(zbuf + (size_t)NNODES * 8);  // 2M words = 8 MB
  float* acc           = (float*)(ebm + BM_WORDS);           // acc[0]=nll sum, acc[1]=kl

  k_init<<<64, 1024, 0, stream>>>(cnt, acc, ebm);
  k_build<<<1024, 256, 0, stream>>>(ei, cnt, colb, ebm);
  k_gin<<<256, 1024, 0, stream>>>(x, eps, cnt, colb,
                                  W0a, b0a, W0b, b0b, Wa, ba, Wb, bb,
                                  Wm, bm, Ws, bs, ebm, zbuf, acc, out);
  k_adj<<<4096, 256, 0, stream>>>(zbuf, ebm, out, acc);
  k_fin<<<1, 64, 0, stream>>>(acc, out);
}